// Round 5
// baseline (317.214 us; speedup 1.0000x reference)
//
#include <hip/hip_runtime.h>
#include <cstdint>
#include <cstddef>

// ---------- types ----------
typedef float  f32x4_t  __attribute__((ext_vector_type(4)));
typedef __bf16 bf16x8_t __attribute__((ext_vector_type(8)));
typedef __bf16 bf16x4_t __attribute__((ext_vector_type(4)));

#define NTOK   65536   // B*T*H*W = 4*16*32*32
#define CCH    256
#define NWINT  1024    // total windows (B*256)

// ---------- helpers ----------
__device__ __forceinline__ float wred_sum(float v) {
#pragma unroll
  for (int off = 32; off > 0; off >>= 1) v += __shfl_xor(v, off, 64);
  return v;
}

// async global->LDS, 16B per lane; lds dest must be wave-uniform (HW adds lane*16)
__device__ __forceinline__ void gload16(void* lds, const void* g) {
  __builtin_amdgcn_global_load_lds(
      (const __attribute__((address_space(1))) uint32_t*)g,
      (__attribute__((address_space(3))) uint32_t*)lds, 16, 0, 0);
}

// windowed-token -> original-token index (roll shift +2 both directions)
__device__ __forceinline__ int win_to_orig(int token) {
  int gid = token >> 6, n = token & 63;
  int bb = gid >> 8, rem = gid & 255;
  int t = (((rem >> 6) << 2) + (n >> 4) + 2) & 15;
  int h = ((((rem >> 3) & 7) << 2) + ((n >> 2) & 3) + 2) & 31;
  int w = (((rem & 7) << 2) + (n & 3) + 2) & 31;
  return ((bb * 16 + t) * 32 + h) * 32 + w;
}

__device__ __forceinline__ float gelu_f(float v) {
  float u = v * (0.7978845608028654f + 0.03567740814f * v * v);
  float t = 1.0f - 2.0f / (__expf(2.0f * u) + 1.0f);
  return 0.5f * v * (1.0f + t);
}

// ---------- weight transpose + bf16 convert ----------
__global__ __launch_bounds__(256) void prep_weights(
    const float* __restrict__ qkv_w, const float* __restrict__ proj_w,
    const float* __restrict__ mlp_w1, const float* __restrict__ mlp_w2,
    __bf16* __restrict__ wt_qkv, __bf16* __restrict__ wt_proj,
    __bf16* __restrict__ wt_mlp1, __bf16* __restrict__ wt_mlp2) {
  int i = blockIdx.x * 256 + threadIdx.x;
  if (i < 196608) {
    int k = i / 768, n = i % 768;
    wt_qkv[n * 256 + k] = (__bf16)qkv_w[i];
  } else if (i < 262144) {
    int j = i - 196608;
    int k = j >> 8, n = j & 255;
    wt_proj[n * 256 + k] = (__bf16)proj_w[j];
  } else if (i < 524288) {
    int j = i - 262144;
    int k = j >> 10, n = j & 1023;
    wt_mlp1[n * 256 + k] = (__bf16)mlp_w1[j];
  } else {
    int j = i - 524288;
    int k = j >> 8, n = j & 255;
    wt_mlp2[n * 1024 + k] = (__bf16)mlp_w2[j];
  }
}

// ---------- bias+mask precompute, fragment-ordered ----------
__global__ __launch_bounds__(256) void cm_prep(
    const float* __restrict__ table, const int* __restrict__ ridx,
    const float* __restrict__ mask, __bf16* __restrict__ cm) {
  int tid = blockIdx.x * 256 + threadIdx.x;  // 0 .. 2M-1
  int l = tid & 63;
  int t16 = (tid >> 6) & 15;
  int h = (tid >> 10) & 7;
  int w = tid >> 13;  // 0..255
  int it = t16 & 3, jt = t16 >> 2;
  int i = it * 16 + (l & 15);
  int jb = jt * 16 + ((l >> 4) << 2);
  const float* mrow = mask + (size_t)w * 4096 + i * 64;
  const int* rrow = ridx + i * 64;
  bf16x4_t o;
#pragma unroll
  for (int r = 0; r < 4; ++r) {
    int j = jb + r;
    o[r] = (__bf16)(table[rrow[j] * 8 + h] + mrow[j]);
  }
  *(bf16x4_t*)(cm + (size_t)tid * 4) = o;
}

// ---------- LayerNorm1 (wave per token, gather rolled+windowed) ----------
__global__ __launch_bounds__(256) void ln_kernel(
    const float* __restrict__ xin, const float* __restrict__ g,
    const float* __restrict__ b, __bf16* __restrict__ out, float eps) {
  int token = blockIdx.x * 4 + (threadIdx.x >> 6);
  int lane = threadIdx.x & 63;
  size_t src = (size_t)win_to_orig(token);
  f32x4_t v = ((const f32x4_t*)(xin + src * CCH))[lane];
  float mu = wred_sum(v[0] + v[1] + v[2] + v[3]) * (1.0f / 256.0f);
  float d0 = v[0] - mu, d1 = v[1] - mu, d2 = v[2] - mu, d3 = v[3] - mu;
  float var = wred_sum(d0 * d0 + d1 * d1 + d2 * d2 + d3 * d3) * (1.0f / 256.0f);
  float rs = rsqrtf(var + eps);
  f32x4_t gg = ((const f32x4_t*)g)[lane];
  f32x4_t bb = ((const f32x4_t*)b)[lane];
  bf16x4_t o;
  o[0] = (__bf16)(d0 * rs * gg[0] + bb[0]);
  o[1] = (__bf16)(d1 * rs * gg[1] + bb[1]);
  o[2] = (__bf16)(d2 * rs * gg[2] + bb[2]);
  o[3] = (__bf16)(d3 * rs * gg[3] + bb[3]);
  *(bf16x4_t*)(out + (size_t)token * CCH + lane * 4) = o;
}

// ---------- QKV GEMM: 128x256 tile, 8 waves, swapped epilogue ----------
#define BMG 128
#define BNG 256
#define BKG 64
__global__ __launch_bounds__(512, 4) void gemm_qkv(
    const __bf16* __restrict__ A, const __bf16* __restrict__ Bt,
    const float* __restrict__ bias, __bf16* __restrict__ outp,
    int N, int K) {
  __shared__ __bf16 smA[BMG * BKG];
  __shared__ __bf16 smB[BNG * BKG];
  const int wv = threadIdx.x >> 6;
  const int ln = threadIdx.x & 63;
  const int i15 = ln & 15, g = ln >> 4;

  int nwg = gridDim.x;
  int wgid = ((int)blockIdx.x & 7) * (nwg >> 3) + ((int)blockIdx.x >> 3);
  int nx = N >> 8;
  int bx = wgid % nx, by = wgid / nx;
  const int bm = by * BMG, bn = bx * BNG;
  const int wr = wv >> 2, wc = wv & 3;

  const __bf16* aP[2];
  const __bf16* bP[4];
#pragma unroll
  for (int it = 0; it < 2; ++it) {
    int slot = (it * 8 + wv) * 64 + ln;
    int row = slot >> 3, chunk = (slot & 7) ^ (row & 7);
    aP[it] = A + (size_t)(bm + row) * K + chunk * 8;
  }
#pragma unroll
  for (int it = 0; it < 4; ++it) {
    int slot = (it * 8 + wv) * 64 + ln;
    int row = slot >> 3, chunk = (slot & 7) ^ (row & 7);
    bP[it] = Bt + (size_t)(bn + row) * K + chunk * 8;
  }

  f32x4_t acc[4][4];  // [nn][mm]
#pragma unroll
  for (int nn = 0; nn < 4; ++nn)
#pragma unroll
    for (int mm = 0; mm < 4; ++mm) acc[nn][mm] = (f32x4_t){0.f, 0.f, 0.f, 0.f};

  const int KT = K >> 6;
  for (int kt = 0; kt < KT; ++kt) {
#pragma unroll
    for (int it = 0; it < 2; ++it) {
      gload16(&smA[(it * 8 + wv) * 512], aP[it]);
      aP[it] += BKG;
    }
#pragma unroll
    for (int it = 0; it < 4; ++it) {
      gload16(&smB[(it * 8 + wv) * 512], bP[it]);
      bP[it] += BKG;
    }
    asm volatile("s_waitcnt vmcnt(0)" ::: "memory");
    __syncthreads();

#pragma unroll
    for (int kh = 0; kh < 2; ++kh) {
      int co = ((kh * 4 + g) ^ (i15 & 7)) * 16;
      bf16x8_t af[4], bfr[4];
#pragma unroll
      for (int mm = 0; mm < 4; ++mm)
        af[mm] = *(const bf16x8_t*)((const char*)smA +
                                    (wr * 64 + mm * 16 + i15) * 128 + co);
#pragma unroll
      for (int nn = 0; nn < 4; ++nn)
        bfr[nn] = *(const bf16x8_t*)((const char*)smB +
                                     (wc * 64 + nn * 16 + i15) * 128 + co);
#pragma unroll
      for (int nn = 0; nn < 4; ++nn)
#pragma unroll
        for (int mm = 0; mm < 4; ++mm)
          acc[nn][mm] = __builtin_amdgcn_mfma_f32_16x16x32_bf16(
              bfr[nn], af[mm], acc[nn][mm], 0, 0, 0);
    }
    __syncthreads();
  }

  // swapped epilogue: lane holds 4 consecutive cols at row (.. + i15)
#pragma unroll
  for (int nn = 0; nn < 4; ++nn) {
    int colg = bn + wc * 64 + nn * 16 + g * 4;
    f32x4_t bv = *(const f32x4_t*)(bias + colg);
#pragma unroll
    for (int mm = 0; mm < 4; ++mm) {
      int rowg = bm + wr * 64 + mm * 16 + i15;
      bf16x4_t o;
#pragma unroll
      for (int r = 0; r < 4; ++r) o[r] = (__bf16)(acc[nn][mm][r] + bv[r]);
      *(bf16x4_t*)(outp + (size_t)rowg * N + colg) = o;
    }
  }
}

// ---------- proj GEMM + scatter + residual + LN2 fused ----------
// A = owin (M x 256), Bt = proj_w^T (256 x 256), res = x (orig order).
// Writes x2 (f32, orig order) and yb = LN2(x2) (bf16, orig order).
__global__ __launch_bounds__(512, 2) void proj_ln(
    const __bf16* __restrict__ A, const __bf16* __restrict__ Bt,
    const float* __restrict__ bias, const float* __restrict__ res,
    const float* __restrict__ g2, const float* __restrict__ b2,
    float* __restrict__ x2, __bf16* __restrict__ yb) {
  __shared__ __bf16 smA[BMG * BKG];
  __shared__ __bf16 smB[BNG * BKG];
  const int wv = threadIdx.x >> 6;
  const int ln = threadIdx.x & 63;
  const int i15 = ln & 15, g = ln >> 4;

  int nwg = gridDim.x;
  int wgid = ((int)blockIdx.x & 7) * (nwg >> 3) + ((int)blockIdx.x >> 3);
  const int bm = wgid * BMG;  // N=256 -> single col-block
  const int wr = wv >> 2, wc = wv & 3;
  const int K = 256;

  const __bf16* aP[2];
  const __bf16* bP[4];
#pragma unroll
  for (int it = 0; it < 2; ++it) {
    int slot = (it * 8 + wv) * 64 + ln;
    int row = slot >> 3, chunk = (slot & 7) ^ (row & 7);
    aP[it] = A + (size_t)(bm + row) * K + chunk * 8;
  }
#pragma unroll
  for (int it = 0; it < 4; ++it) {
    int slot = (it * 8 + wv) * 64 + ln;
    int row = slot >> 3, chunk = (slot & 7) ^ (row & 7);
    bP[it] = Bt + (size_t)row * K + chunk * 8;
  }

  f32x4_t acc[4][4];  // [nn][mm]
#pragma unroll
  for (int nn = 0; nn < 4; ++nn)
#pragma unroll
    for (int mm = 0; mm < 4; ++mm) acc[nn][mm] = (f32x4_t){0.f, 0.f, 0.f, 0.f};

  for (int kt = 0; kt < 4; ++kt) {
#pragma unroll
    for (int it = 0; it < 2; ++it) {
      gload16(&smA[(it * 8 + wv) * 512], aP[it]);
      aP[it] += BKG;
    }
#pragma unroll
    for (int it = 0; it < 4; ++it) {
      gload16(&smB[(it * 8 + wv) * 512], bP[it]);
      bP[it] += BKG;
    }
    asm volatile("s_waitcnt vmcnt(0)" ::: "memory");
    __syncthreads();
#pragma unroll
    for (int kh = 0; kh < 2; ++kh) {
      int co = ((kh * 4 + g) ^ (i15 & 7)) * 16;
      bf16x8_t af[4], bfr[4];
#pragma unroll
      for (int mm = 0; mm < 4; ++mm)
        af[mm] = *(const bf16x8_t*)((const char*)smA +
                                    (wr * 64 + mm * 16 + i15) * 128 + co);
#pragma unroll
      for (int nn = 0; nn < 4; ++nn)
        bfr[nn] = *(const bf16x8_t*)((const char*)smB +
                                     (wc * 64 + nn * 16 + i15) * 128 + co);
#pragma unroll
      for (int nn = 0; nn < 4; ++nn)
#pragma unroll
        for (int mm = 0; mm < 4; ++mm)
          acc[nn][mm] = __builtin_amdgcn_mfma_f32_16x16x32_bf16(
              bfr[nn], af[mm], acc[nn][mm], 0, 0, 0);
    }
    __syncthreads();
  }

  // fold bias + residual (scattered rows)
  size_t dst[4];
#pragma unroll
  for (int mm = 0; mm < 4; ++mm) {
    int rowg = bm + wr * 64 + mm * 16 + i15;
    dst[mm] = (size_t)win_to_orig(rowg) * CCH;
  }
#pragma unroll
  for (int nn = 0; nn < 4; ++nn) {
    int colg = wc * 64 + nn * 16 + g * 4;
    f32x4_t bv = *(const f32x4_t*)(bias + colg);
#pragma unroll
    for (int mm = 0; mm < 4; ++mm) {
      f32x4_t rv = *(const f32x4_t*)(res + dst[mm] + colg);
#pragma unroll
      for (int r = 0; r < 4; ++r) acc[nn][mm][r] += bv[r] + rv[r];
    }
  }

  // LN2 stats: per row (mm, i15): sum over nn,r in-lane, over g via shfl,
  // over wc via LDS
  float2* stf = (float2*)smA;  // 128 rows x 4 waves, 4KB (smA dead)
#pragma unroll
  for (int mm = 0; mm < 4; ++mm) {
    float s1 = 0.f, s2 = 0.f;
#pragma unroll
    for (int nn = 0; nn < 4; ++nn)
#pragma unroll
      for (int r = 0; r < 4; ++r) {
        float v = acc[nn][mm][r];
        s1 += v;
        s2 += v * v;
      }
    s1 += __shfl_xor(s1, 16, 64);
    s1 += __shfl_xor(s1, 32, 64);
    s2 += __shfl_xor(s2, 16, 64);
    s2 += __shfl_xor(s2, 32, 64);
    if (g == 0) stf[(wr * 64 + mm * 16 + i15) * 4 + wc] = make_float2(s1, s2);
  }
  __syncthreads();
  float mu[4], rs[4];
#pragma unroll
  for (int mm = 0; mm < 4; ++mm) {
    int row = wr * 64 + mm * 16 + i15;
    float S1 = 0.f, S2 = 0.f;
#pragma unroll
    for (int w = 0; w < 4; ++w) {
      float2 p = stf[row * 4 + w];
      S1 += p.x;
      S2 += p.y;
    }
    mu[mm] = S1 * (1.0f / 256.0f);
    rs[mm] = rsqrtf(S2 * (1.0f / 256.0f) - mu[mm] * mu[mm] + 1e-6f);
  }

  // stores: x2 (f32x4) + yb (bf16x4)
#pragma unroll
  for (int nn = 0; nn < 4; ++nn) {
    int colg = wc * 64 + nn * 16 + g * 4;
    f32x4_t gv = *(const f32x4_t*)(g2 + colg);
    f32x4_t bv = *(const f32x4_t*)(b2 + colg);
#pragma unroll
    for (int mm = 0; mm < 4; ++mm) {
      f32x4_t v = acc[nn][mm];
      *(f32x4_t*)(x2 + dst[mm] + colg) = v;
      bf16x4_t yo;
#pragma unroll
      for (int r = 0; r < 4; ++r)
        yo[r] = (__bf16)((v[r] - mu[mm]) * rs[mm] * gv[r] + bv[r]);
      *(bf16x4_t*)(yb + dst[mm] + colg) = yo;
    }
  }
}

// ---------- fused MLP: out += gelu(y@W1+b1)@W2 + b2 (h1 stays in LDS) ----------
// 64 rows/block, 4 waves (wave = N-quarter). h1 chunked 4x256.
__global__ __launch_bounds__(256, 2) void mlp_fused(
    const __bf16* __restrict__ yb, const __bf16* __restrict__ w1t,
    const float* __restrict__ b1, const __bf16* __restrict__ w2t,
    const float* __restrict__ b2, float* __restrict__ io) {
  __shared__ __bf16 smA[64 * 64];    // 8 KB  y-tile
  __shared__ __bf16 smW[256 * 64];   // 32 KB W1/W2 tile (time-shared)
  __shared__ __bf16 h1b[64 * 256];   // 32 KB h1 chunk, XOR-swizzled
  const int wv = threadIdx.x >> 6;
  const int ln = threadIdx.x & 63;
  const int i15 = ln & 15, g = ln >> 4, wc = wv;

  int nwg = gridDim.x;
  int wgid = ((int)blockIdx.x & 7) * (nwg >> 3) + ((int)blockIdx.x >> 3);
  const int bm = wgid * 64;

  uint32_t aOff[2], w1o[8], w2o[8];
#pragma unroll
  for (int rnd = 0; rnd < 2; ++rnd) {
    int slot = rnd * 256 + (int)threadIdx.x;
    int row = slot >> 3, ch = (slot & 7) ^ (row & 7);
    aOff[rnd] = (uint32_t)((bm + row) * 256 + ch * 8);
  }
#pragma unroll
  for (int rnd = 0; rnd < 8; ++rnd) {
    int slot = rnd * 256 + (int)threadIdx.x;
    int row = slot >> 3, ch = (slot & 7) ^ (row & 7);
    w1o[rnd] = (uint32_t)(row * 256 + ch * 8);
    w2o[rnd] = (uint32_t)(row * 1024 + ch * 8);
  }

  f32x4_t acc2[4][4];  // [nn][mm], persists over nc
#pragma unroll
  for (int nn = 0; nn < 4; ++nn)
#pragma unroll
    for (int mm = 0; mm < 4; ++mm) acc2[nn][mm] = (f32x4_t){0.f, 0.f, 0.f, 0.f};

  for (int nc = 0; nc < 4; ++nc) {
    f32x4_t acc1[4][4];
#pragma unroll
    for (int nn = 0; nn < 4; ++nn)
#pragma unroll
      for (int mm = 0; mm < 4; ++mm)
        acc1[nn][mm] = (f32x4_t){0.f, 0.f, 0.f, 0.f};

    // ---- phase 1: h1chunk = y @ W1[:, nc*256..] ----
    for (int kt = 0; kt < 4; ++kt) {
#pragma unroll
      for (int rnd = 0; rnd < 2; ++rnd)
        gload16(&smA[(rnd * 4 + wv) * 512], yb + aOff[rnd] + kt * 64);
#pragma unroll
      for (int rnd = 0; rnd < 8; ++rnd)
        gload16(&smW[(rnd * 4 + wv) * 512],
                w1t + nc * 65536 + w1o[rnd] + kt * 64);
      asm volatile("s_waitcnt vmcnt(0)" ::: "memory");
      __syncthreads();
#pragma unroll
      for (int kh = 0; kh < 2; ++kh) {
        int co = ((kh * 4 + g) ^ (i15 & 7)) * 16;
        bf16x8_t af[4], wf[4];
#pragma unroll
        for (int mm = 0; mm < 4; ++mm)
          af[mm] = *(const bf16x8_t*)((const char*)smA +
                                      (mm * 16 + i15) * 128 + co);
#pragma unroll
        for (int nn = 0; nn < 4; ++nn)
          wf[nn] = *(const bf16x8_t*)((const char*)smW +
                                      (wc * 64 + nn * 16 + i15) * 128 + co);
#pragma unroll
        for (int nn = 0; nn < 4; ++nn)
#pragma unroll
          for (int mm = 0; mm < 4; ++mm)
            acc1[nn][mm] = __builtin_amdgcn_mfma_f32_16x16x32_bf16(
                wf[nn], af[mm], acc1[nn][mm], 0, 0, 0);
      }
      __syncthreads();
    }

    // prefetch W2 (kt2=0) overlapped with GELU
#pragma unroll
    for (int rnd = 0; rnd < 8; ++rnd)
      gload16(&smW[(rnd * 4 + wv) * 512], w2t + w2o[rnd] + nc * 256);

    // GELU + h1 write (swizzled: byte ^= (row&7)<<4, row&7 == i15&7)
    const float* b1g = b1 + nc * 256 + wc * 64;
#pragma unroll
    for (int nn = 0; nn < 4; ++nn) {
      f32x4_t bb = *(const f32x4_t*)(b1g + nn * 16 + g * 4);
#pragma unroll
      for (int mm = 0; mm < 4; ++mm) {
        bf16x4_t p;
#pragma unroll
        for (int r = 0; r < 4; ++r)
          p[r] = (__bf16)gelu_f(acc1[nn][mm][r] + bb[r]);
        uint32_t byte =
            (uint32_t)((mm * 16 + i15) * 512 +
                       ((wc * 128 + nn * 32 + g * 8) ^ ((i15 & 7) << 4)));
        *(bf16x4_t*)((char*)h1b + byte) = p;
      }
    }

    // ---- phase 2: acc2 += h1chunk @ W2[k-slice nc] ----
    for (int kt2 = 0; kt2 < 4; ++kt2) {
      asm volatile("s_waitcnt vmcnt(0)" ::: "memory");
      __syncthreads();  // W2(kt2) landed; h1 writes visible (1st iter)
#pragma unroll
      for (int kh = 0; kh < 2; ++kh) {
        int coW = ((kh * 4 + g) ^ (i15 & 7)) * 16;
        int coA = kt2 * 128 + ((kh * 64 + g * 16) ^ ((i15 & 7) << 4));
        bf16x8_t af[4], wf[4];
#pragma unroll
        for (int mm = 0; mm < 4; ++mm)
          af[mm] = *(const bf16x8_t*)((const char*)h1b +
                                      (mm * 16 + i15) * 512 + coA);
#pragma unroll
        for (int nn = 0; nn < 4; ++nn)
          wf[nn] = *(const bf16x8_t*)((const char*)smW +
                                      (wc * 64 + nn * 16 + i15) * 128 + coW);
#pragma unroll
        for (int nn = 0; nn < 4; ++nn)
#pragma unroll
          for (int mm = 0; mm < 4; ++mm)
            acc2[nn][mm] = __builtin_amdgcn_mfma_f32_16x16x32_bf16(
                wf[nn], af[mm], acc2[nn][mm], 0, 0, 0);
      }
      __syncthreads();  // reads drained before smW/h1b overwrite
      if (kt2 < 3) {
#pragma unroll
        for (int rnd = 0; rnd < 8; ++rnd)
          gload16(&smW[(rnd * 4 + wv) * 512],
                  w2t + w2o[rnd] + nc * 256 + (kt2 + 1) * 64);
      }
    }
  }

  // epilogue: out = res + acc2 + b2  (f32x4 in-place on d_out)
#pragma unroll
  for (int nn = 0; nn < 4; ++nn) {
    int colg = wc * 64 + nn * 16 + g * 4;
    f32x4_t bb = *(const f32x4_t*)(b2 + colg);
#pragma unroll
    for (int mm = 0; mm < 4; ++mm) {
      int rowg = bm + mm * 16 + i15;
      float* p = io + (size_t)rowg * 256 + colg;
      f32x4_t rv = *(const f32x4_t*)p;
      f32x4_t o;
#pragma unroll
      for (int r = 0; r < 4; ++r) o[r] = rv[r] + acc2[nn][mm][r] + bb[r];
      *(f32x4_t*)p = o;
    }
  }
}

// ---------- MFMA windowed attention: 1 wave per (window, head) ----------
__global__ __launch_bounds__(256) void attn_mfma(
    const __bf16* __restrict__ qkv, const __bf16* __restrict__ cm,
    __bf16* __restrict__ owin) {
  __shared__ __align__(16) __bf16 smP[4][64 * 72];  // P, padded stride 72
  __shared__ __align__(16) __bf16 smV[4][64 * 32];  // V, linear rows
  const int wv = threadIdx.x >> 6;
  const int ln = threadIdx.x & 63;
  const int task = blockIdx.x * 4 + wv;  // 0..8191
  const int win = task >> 3;
  const int h = task & 7;
  const int i15 = ln & 15, g = ln >> 4;

  const __bf16* base = qkv + (size_t)win * 64 * 768 + h * 32;

  {
    __bf16* vdst = smV[wv];
#pragma unroll
    for (int c = 0; c < 4; ++c) {
      const __bf16* src =
          base + (size_t)(c * 16 + (ln >> 2)) * 768 + 512 + (ln & 3) * 8;
      gload16(vdst + c * 512, src);
    }
  }

  bf16x8_t kf[4], qf[4];
#pragma unroll
  for (int t = 0; t < 4; ++t) {
    kf[t] = *(const bf16x8_t*)(base + (size_t)(t * 16 + i15) * 768 + 256 + g * 8);
    qf[t] = *(const bf16x8_t*)(base + (size_t)(t * 16 + i15) * 768 + g * 8);
  }

  f32x4_t st[4][4];
#pragma unroll
  for (int jt = 0; jt < 4; ++jt)
#pragma unroll
    for (int it = 0; it < 4; ++it)
      st[jt][it] = __builtin_amdgcn_mfma_f32_16x16x32_bf16(
          kf[jt], qf[it], (f32x4_t){0.f, 0.f, 0.f, 0.f}, 0, 0, 0);

  const __bf16* cmp = cm + (((size_t)(win & 255) * 8 + h) * 16) * 256;
#pragma unroll
  for (int jt = 0; jt < 4; ++jt)
#pragma unroll
    for (int it = 0; it < 4; ++it) {
      bf16x4_t c4 = *(const bf16x4_t*)(cmp + ((jt * 4 + it) * 64 + ln) * 4);
#pragma unroll
      for (int r = 0; r < 4; ++r)
        st[jt][it][r] =
            fmaf(st[jt][it][r], 0.17677669529663687f, (float)c4[r]);
    }

#pragma unroll
  for (int it = 0; it < 4; ++it) {
    float mx = -1e30f;
#pragma unroll
    for (int jt = 0; jt < 4; ++jt)
#pragma unroll
      for (int r = 0; r < 4; ++r) mx = fmaxf(mx, st[jt][it][r]);
    mx = fmaxf(mx, __shfl_xor(mx, 16, 64));
    mx = fmaxf(mx, __shfl_xor(mx, 32, 64));
    float sum = 0.f;
#pragma unroll
    for (int jt = 0; jt < 4; ++jt)
#pragma unroll
      for (int r = 0; r < 4; ++r) {
        float p = __expf(st[jt][it][r] - mx);
        st[jt][it][r] = p;
        sum += p;
      }
    sum += __shfl_xor(sum, 16, 64);
    sum += __shfl_xor(sum, 32, 64);
    float inv = 1.0f / sum;
#pragma unroll
    for (int jt = 0; jt < 4; ++jt) {
      bf16x4_t p4;
#pragma unroll
      for (int r = 0; r < 4; ++r) p4[r] = (__bf16)(st[jt][it][r] * inv);
      *(bf16x4_t*)(smP[wv] + (it * 16 + i15) * 72 + jt * 16 + g * 4) = p4;
    }
  }
  __syncthreads();

  f32x4_t oacc[4][2];
#pragma unroll
  for (int it = 0; it < 4; ++it)
#pragma unroll
    for (int dt = 0; dt < 2; ++dt) oacc[it][dt] = (f32x4_t){0.f, 0.f, 0.f, 0.f};

  const __bf16* pl = smP[wv];
  const __bf16* vl = smV[wv];
#pragma unroll
  for (int kt = 0; kt < 2; ++kt) {
    bf16x8_t vf[2];
#pragma unroll
    for (int dt = 0; dt < 2; ++dt)
#pragma unroll
      for (int e = 0; e < 8; ++e)
        vf[dt][e] = vl[(kt * 32 + g * 8 + e) * 32 + dt * 16 + i15];
#pragma unroll
    for (int it = 0; it < 4; ++it) {
      bf16x8_t pa =
          *(const bf16x8_t*)(pl + (it * 16 + i15) * 72 + kt * 32 + g * 8);
#pragma unroll
      for (int dt = 0; dt < 2; ++dt)
        oacc[it][dt] = __builtin_amdgcn_mfma_f32_16x16x32_bf16(
            pa, vf[dt], oacc[it][dt], 0, 0, 0);
    }
  }

  __bf16* op = owin + (size_t)win * 64 * 256 + h * 32;
#pragma unroll
  for (int it = 0; it < 4; ++it)
#pragma unroll
    for (int r = 0; r < 4; ++r) {
      int i = it * 16 + g * 4 + r;
#pragma unroll
      for (int dt = 0; dt < 2; ++dt)
        op[(size_t)i * 256 + dt * 16 + i15] = (__bf16)oacc[it][dt][r];
    }
}

// ---------- launch ----------
extern "C" void kernel_launch(void* const* d_in, const int* in_sizes, int n_in,
                              void* d_out, int out_size, void* d_ws,
                              size_t ws_size, hipStream_t stream) {
  (void)in_sizes; (void)n_in; (void)out_size; (void)ws_size;
  const float* x      = (const float*)d_in[0];
  const float* n1g    = (const float*)d_in[1];
  const float* n1b    = (const float*)d_in[2];
  const float* qkv_w  = (const float*)d_in[3];
  const float* qkv_b  = (const float*)d_in[4];
  const float* proj_w = (const float*)d_in[5];
  const float* proj_b = (const float*)d_in[6];
  const float* rbt    = (const float*)d_in[7];
  const float* n2g    = (const float*)d_in[8];
  const float* n2b    = (const float*)d_in[9];
  const float* mlp_w1 = (const float*)d_in[10];
  const float* mlp_b1 = (const float*)d_in[11];
  const float* mlp_w2 = (const float*)d_in[12];
  const float* mlp_b2 = (const float*)d_in[13];
  const int*   ridx   = (const int*)d_in[14];
  const float* amask  = (const float*)d_in[15];

  char* ws = (char*)d_ws;
  size_t off = 0;
  auto alloc = [&](size_t bytes) {
    void* p = ws + off;
    off += (bytes + 255) & ~(size_t)255;
    return p;
  };
  __bf16* wt_qkv  = (__bf16*)alloc(768 * 256 * 2);
  __bf16* wt_proj = (__bf16*)alloc(256 * 256 * 2);
  __bf16* wt_mlp1 = (__bf16*)alloc(1024 * 256 * 2);
  __bf16* wt_mlp2 = (__bf16*)alloc(1024 * 256 * 2);
  __bf16* hwin = (__bf16*)alloc((size_t)NTOK * 256 * 2);  // LN1 out; reused: cm, then yb
  __bf16* qkv  = (__bf16*)alloc((size_t)NTOK * 768 * 2);
  __bf16* owin = (__bf16*)alloc((size_t)NTOK * 256 * 2);
  __bf16* cmb  = hwin;
  __bf16* yb   = hwin;
  float* x2    = (float*)d_out;

  prep_weights<<<3072, 256, 0, stream>>>(qkv_w, proj_w, mlp_w1, mlp_w2,
                                         wt_qkv, wt_proj, wt_mlp1, wt_mlp2);
  ln_kernel<<<NTOK / 4, 256, 0, stream>>>(x, n1g, n1b, hwin, 1e-5f);
  gemm_qkv<<<3 * (NTOK / BMG), 512, 0, stream>>>(hwin, wt_qkv, qkv_b, qkv,
                                                 768, 256);
  cm_prep<<<8192, 256, 0, stream>>>(rbt, ridx, amask, cmb);
  attn_mfma<<<2048, 256, 0, stream>>>(qkv, cmb, owin);
  proj_ln<<<NTOK / BMG, 512, 0, stream>>>(owin, wt_proj, proj_b, x, n2g, n2b,
                                          x2, yb);
  mlp_fused<<<NTOK / 64, 256, 0, stream>>>(yb, wt_mlp1, mlp_b1, wt_mlp2,
                                           mlp_b2, x2);
}